// Round 9
// baseline (332.742 us; speedup 1.0000x reference)
//
#include <hip/hip_runtime.h>

// ChildSumTreeLSTM, complete 8-ary tree, 7 levels, N=299593, MEM=150, IN=300.
// Level d occupies [(8^d-1)/7, (8^(d+1)-1)/7); children of p: 8p+1..8p+8.
// v9: leaf level collapsed into per-vocab tables. For a leaf token v:
//   c_leaf(v)=sigm(i)tanh(u), h_leaf(v)=sigm(o)tanh(c_leaf), fh(v)=Wfh·h_leaf.
// fh stored fp8 e4m3 (7.6MB). leaf_csum gathers tables per level-5 parent and
// emits c_out / h_sum / sum(f*c) with no MFMA and no barriers.

#define MEMD  150
#define IND   300
#define NINT  37449
#define VOCAB 50000
#define GROW  600          // ushorts per gall row: 150 cols x 4 gates
#define FSTR  152          // hsum/fcsum/fhx/htmp row stride (elements)

typedef short bf16x8 __attribute__((ext_vector_type(8)));
typedef float f32x16 __attribute__((ext_vector_type(16)));
#define ZERO16 {0,0,0,0,0,0,0,0,0,0,0,0,0,0,0,0}

// ws layout (bytes); high-water 91,004,800 <= 95.87MB proven safe
#define GALL_OFF 0ul           // ushort [VOCAB][600]
#define FHX_OFF  60000000ul    // u8 fp8 [VOCAB][152]
#define HSB_OFF  67600000ul    // bf16 [NINT][152]; htmp [VOCAB][152] aliases here
#define FCS_OFF  79000000ul    // bf16 [NINT][152]
#define BPX_OFF  90400000ul    // bf16 B-frags x-side [4][5][19][64][8]
#define BPH_OFF  90800000ul    // bf16 B-frags h-side [4][5][10][64][8]

__device__ __forceinline__ float b2f(unsigned short u) {
    union { unsigned int i; float f; } v; v.i = ((unsigned int)u) << 16; return v.f;
}
__device__ __forceinline__ unsigned short f2b(float f) {
    union { float f; unsigned int i; } v; v.f = f;
    unsigned int x = v.i;
    x += 0x7fffu + ((x >> 16) & 1u);
    return (unsigned short)(x >> 16);
}
__device__ __forceinline__ float sigm(float x) {
    return __builtin_amdgcn_rcpf(1.0f + __expf(-x));
}
__device__ __forceinline__ float tanh_fast(float x) {
    float e = __expf(2.0f * x);
    return 1.0f - 2.0f * __builtin_amdgcn_rcpf(e + 1.0f);
}
// fp8 e4m3fn helpers
__device__ __forceinline__ unsigned char f2e4m3(float f) {
    union { float f; unsigned u; } v; v.f = f;
    unsigned s = (v.u >> 31) << 7;
    float af = fabsf(f);
    if (af >= 448.f) return (unsigned char)(s | 0x7E);
    if (af < 0.015625f) {
        int m = (int)(af * 512.f + 0.5f);
        if (m > 7) m = 7;
        return (unsigned char)(s | m);
    }
    unsigned u = v.u & 0x7fffffffu;
    u += 0x7ffffu + ((u >> 20) & 1u);
    int ef = (int)(u >> 23) - 120;
    unsigned m = (u >> 20) & 7u;
    if (ef < 1) { ef = 1; m = 0; }
    if (ef > 15) { ef = 15; m = 6; }
    return (unsigned char)(s | (ef << 3) | m);
}
__device__ __forceinline__ float e4m3f(unsigned char u) {
    unsigned s = (u >> 7) & 1u, ef = (u >> 3) & 15u, m = u & 7u;
    if (ef == 0) {
        float r = (float)m * 0.001953125f;
        return s ? -r : r;
    }
    union { unsigned u; float f; } v;
    v.u = (s << 31) | ((ef + 120) << 23) | (m << 20);
    return v.f;
}

// ---- pack weights into 32x32x16 B-fragment order (verified R3-R8) ----
__global__ void pack_w(const float* __restrict__ Wix, const float* __restrict__ Wox,
                       const float* __restrict__ Wux, const float* __restrict__ Wfx,
                       const float* __restrict__ Wih, const float* __restrict__ Woh,
                       const float* __restrict__ Wuh, const float* __restrict__ Wfh,
                       unsigned short* __restrict__ bpx, unsigned short* __restrict__ bph)
{
    const int total_x = 4 * 5 * 19 * 512;
    const int total_h = 4 * 5 * 10 * 512;
    for (int i = blockIdx.x * blockDim.x + threadIdx.x; i < total_x + total_h;
         i += gridDim.x * blockDim.x) {
        if (i < total_x) {
            int e = i & 7, lane = (i >> 3) & 63, rest = i >> 9;
            int ks = rest % 19; rest /= 19;
            int nt = rest % 5;  int g = rest / 5;
            int col = nt * 32 + (lane & 31);
            int k = ks * 16 + ((lane >> 5) << 3) + e;
            const float* W = (g == 0) ? Wix : (g == 1) ? Wox : (g == 2) ? Wux : Wfx;
            bpx[i] = f2b((col < MEMD && k < IND) ? W[col * IND + k] : 0.f);
        } else {
            int j = i - total_x;
            int e = j & 7, lane = (j >> 3) & 63, rest = j >> 9;
            int ks = rest % 10; rest /= 10;
            int nt = rest % 5;  int g = rest / 5;
            int col = nt * 32 + (lane & 31);
            int k = ks * 16 + ((lane >> 5) << 3) + e;
            const float* W = (g == 0) ? Wih : (g == 1) ? Woh : (g == 2) ? Wuh : Wfh;
            bph[j] = f2b((col < MEMD && k < MEMD) ? W[col * MEMD + k] : 0.f);
        }
    }
}

// ---- per-vocab gate projections: gall[v][col][g], biases folded ----
__global__ __launch_bounds__(640, 2)
void vocab_gemm(const float* __restrict__ emb,
                const float* __restrict__ bix, const float* __restrict__ bih,
                const float* __restrict__ box_, const float* __restrict__ boh,
                const float* __restrict__ bux, const float* __restrict__ buh,
                const float* __restrict__ bfx, const float* __restrict__ bfh,
                const unsigned short* __restrict__ bpx_u,
                unsigned short* __restrict__ gall)
{
    __shared__ __align__(16) char sm0[40960];
    const int tid = threadIdx.x, lane = tid & 63, w = tid >> 6;
    const int hi = lane >> 5, ln31 = lane & 31;
    const int tile0 = blockIdx.x * 64;
    const int rowsValid = min(64, VOCAB - tile0);
    const int mt = (w >= 5) ? 1 : 0, nt = w - mt * 5;

    for (int i = tid; i < 64 * 40; i += 640) {
        int r = i / 40, q = i % 40;
        int rr = (r < rowsValid) ? r : 0;
        const float* er = emb + (long)(tile0 + rr) * IND;
        float4 v0 = {0.f,0.f,0.f,0.f}, v1 = {0.f,0.f,0.f,0.f};
        if (q < 38) v0 = *(const float4*)(er + q * 8);
        if (q < 37) v1 = *(const float4*)(er + q * 8 + 4);
        bf16x8 p;
        p[0]=(short)f2b(v0.x); p[1]=(short)f2b(v0.y); p[2]=(short)f2b(v0.z); p[3]=(short)f2b(v0.w);
        p[4]=(short)f2b(v1.x); p[5]=(short)f2b(v1.y); p[6]=(short)f2b(v1.z); p[7]=(short)f2b(v1.w);
        *(bf16x8*)(sm0 + r * 640 + ((q * 16) ^ ((r & 7) << 4))) = p;
    }
    __syncthreads();

    const bf16x8* BX = (const bf16x8*)bpx_u;
    const int row = mt * 32 + ln31;
    const int col = nt * 32 + ln31;
    const bool colv = col < MEMD;
    const int cc = colv ? col : 0;
    const float* b1[4] = {bix, box_, bux, bfx};
    const float* b2[4] = {bih, boh, buh, bfh};

    for (int g = 0; g < 4; ++g) {
        f32x16 acc = ZERO16;
        bf16x8 aC = *(const bf16x8*)(sm0 + row * 640 + ((hi * 16) ^ ((row & 7) << 4)));
        bf16x8 bC = BX[((g * 5 + nt) * 19 + 0) * 64 + lane];
        #pragma unroll
        for (int ks = 0; ks < 19; ++ks) {
            bf16x8 aN, bN;
            if (ks < 18) {
                aN = *(const bf16x8*)(sm0 + row * 640 + (((ks + 1) * 32 + hi * 16) ^ ((row & 7) << 4)));
                bN = BX[((g * 5 + nt) * 19 + ks + 1) * 64 + lane];
            }
            acc = __builtin_amdgcn_mfma_f32_32x32x16_bf16(aC, bC, acc, 0, 0, 0);
            aC = aN; bC = bN;
        }
        float bias = colv ? (b1[g][cc] + b2[g][cc]) : 0.f;
        #pragma unroll
        for (int r = 0; r < 16; ++r) {
            int rloc = mt * 32 + (r & 3) + 8 * (r >> 2) + 4 * hi;
            if (rloc < rowsValid && colv)
                gall[(long)(tile0 + rloc) * GROW + col * 4 + g] = f2b(acc[r] + bias);
        }
    }
}

// ---- h_leaf(v) from gall -> htmp (bf16, zero-padded cols 150/151) ----
__global__ __launch_bounds__(256, 8)
void hleaf_k(const unsigned short* __restrict__ gall, unsigned short* __restrict__ htmp)
{
    int i = blockIdx.x * 256 + threadIdx.x;
    if (i >= VOCAB * FSTR) return;
    int v = i / FSTR, col = i % FSTR;
    unsigned short r = 0;
    if (col < MEMD) {
        ushort4 gv = *(const ushort4*)(gall + (long)v * GROW + col * 4);
        float iv = sigm(b2f(gv.x));
        float ov = sigm(b2f(gv.y));
        float uv = tanh_fast(b2f(gv.z));
        float cv = iv * uv;
        r = f2b(ov * tanh_fast(cv));
    }
    htmp[i] = r;
}

// ---- fhx(v) = Wfh · h_leaf(v), output fp8 e4m3 ----
__global__ __launch_bounds__(320, 4)
void fhx_gemm(const unsigned short* __restrict__ htmp,
              const unsigned short* __restrict__ bph_u,
              unsigned char* __restrict__ fhx)
{
    __shared__ __align__(16) char sm0[12288];
    const int tid = threadIdx.x, lane = tid & 63, w = tid >> 6;
    const int hi = lane >> 5, ln31 = lane & 31;
    const int tile0 = blockIdx.x * 32;
    const int rowsValid = min(32, VOCAB - tile0);
    const int nt = w;

    for (int i = tid; i < 32 * 20; i += 320) {
        int r = i / 20, q = i % 20;
        int rr = (r < rowsValid) ? r : 0;
        bf16x8 v = {0,0,0,0,0,0,0,0};
        if (q < 19) v = *(const bf16x8*)(htmp + (long)(tile0 + rr) * FSTR + q * 8);
        *(bf16x8*)(sm0 + r * 384 + ((q * 16) ^ ((r & 7) << 4))) = v;
    }
    __syncthreads();

    const bf16x8* BH = (const bf16x8*)bph_u;
    const int row = ln31;
    f32x16 ff = ZERO16;
    #pragma unroll
    for (int ks = 0; ks < 10; ++ks) {
        bf16x8 a = *(const bf16x8*)(sm0 + row * 384 + ((ks * 32 + hi * 16) ^ ((row & 7) << 4)));
        ff = __builtin_amdgcn_mfma_f32_32x32x16_bf16(a, BH[((15 + nt) * 10 + ks) * 64 + lane], ff, 0, 0, 0);
    }
    const int col = nt * 32 + ln31;
    if (col < MEMD) {
        #pragma unroll
        for (int r = 0; r < 16; ++r) {
            int rloc = (r & 3) + 8 * (r >> 2) + 4 * hi;
            if (rloc < rowsValid)
                fhx[(long)(tile0 + rloc) * FSTR + col] = f2e4m3(ff[r]);
        }
    }
}

// ---- leaf level: table gathers only; emits c_out, h_sum, sum(f*c) ----
__global__ __launch_bounds__(320, 8)
void leaf_csum(const int* __restrict__ tokens,
               const unsigned short* __restrict__ gall,
               const unsigned char* __restrict__ fhx,
               unsigned short* __restrict__ hsumb, unsigned short* __restrict__ fcs,
               float* __restrict__ c_out)
{
    __shared__ int ctok[16];
    __shared__ int ptokL[2];
    const int tid = threadIdx.x;
    const int pl = tid / 160;
    const int col0 = tid % 160;
    const bool colv = col0 < MEMD;
    const int col = colv ? col0 : (MEMD - 1);
    const int pidx = blockIdx.x * 2 + pl;
    const int pnode = 4681 + pidx;
    const long cbase = 8L * pnode + 1;          // contiguous leaf children
    if (tid < 16) ctok[tid] = tokens[37449 + blockIdx.x * 16 + tid];
    if (tid < 2)  ptokL[tid] = tokens[4681 + blockIdx.x * 2 + tid];
    __syncthreads();

    const float fxp = b2f(gall[(long)ptokL[pl] * GROW + col * 4 + 3]);
    float hs = 0.f, fc = 0.f;
    #pragma unroll
    for (int k = 0; k < 8; ++k) {
        int ct = ctok[pl * 8 + k];
        ushort4 gv = *(const ushort4*)(gall + (long)ct * GROW + col * 4);
        float iv = sigm(b2f(gv.x));
        float ov = sigm(b2f(gv.y));
        float uv = tanh_fast(b2f(gv.z));
        float cv = iv * uv;
        float h = ov * tanh_fast(cv);
        float f = sigm(e4m3f(fhx[(long)ct * FSTR + col]) + fxp);
        hs += h;
        fc += f * cv;
        if (colv) c_out[(cbase + k) * MEMD + col] = cv;
    }
    if (colv) {
        hsumb[(long)pnode * FSTR + col] = f2b(hs);
        fcs[(long)pnode * FSTR + col]  = f2b(fc);
    }
}

// ---- internal-level kernel (levels 5..3): x gathered, h via MFMA ----
__global__ __launch_bounds__(320, 2)
void level_k(const int* __restrict__ tokens,
             const unsigned short* __restrict__ gall,
             const unsigned short* __restrict__ bph_u,
             unsigned short* __restrict__ hsumb, unsigned short* __restrict__ fcsum,
             float* __restrict__ c_out, int base, int cnt, int writePar)
{
    __shared__ __align__(16) char sm0[24576];
    __shared__ int toksL[32];
    __shared__ int ptokL[4];
    const int tid = threadIdx.x, lane = tid & 63, w = tid >> 6;
    const int hi = lane >> 5, ln31 = lane & 31;
    const int tile0 = blockIdx.x * 32;
    const int nodeBase = base + tile0;
    const int rowsValid = min(32, cnt - tile0);
    const int p0 = (nodeBase - 1) >> 3;
    const int nt = w;

    if (tid < 32) toksL[tid] = tokens[nodeBase + ((tid < rowsValid) ? tid : 0)];
    if (writePar && tid < 4) ptokL[tid] = tokens[p0 + tid];
    for (int i = tid; i < 32 * 20; i += 320) {
        int r = i / 20, q = i % 20;
        int rr = (r < rowsValid) ? r : 0;
        bf16x8 v = {0,0,0,0,0,0,0,0};
        if (q < 19)
            v = *(const bf16x8*)(hsumb + (long)(nodeBase + rr) * FSTR + q * 8);
        *(bf16x8*)(sm0 + 12288 + r * 384 + ((q * 16) ^ ((r & 7) << 4))) = v;
    }
    __syncthreads();

    const bf16x8* BH = (const bf16x8*)bph_u;
    const int row = ln31;
    const int col = nt * 32 + ln31;
    const bool colv = col < MEMD;
    const int cc = colv ? col : 0;

    f32x16 ai = ZERO16, ao = ZERO16, au = ZERO16;
    {
        const char* hb = sm0 + 12288;
        bf16x8 aC = *(const bf16x8*)(hb + row * 384 + ((hi * 16) ^ ((row & 7) << 4)));
        bf16x8 b0C = BH[((0 * 5 + nt) * 10 + 0) * 64 + lane];
        bf16x8 b1C = BH[((1 * 5 + nt) * 10 + 0) * 64 + lane];
        bf16x8 b2C = BH[((2 * 5 + nt) * 10 + 0) * 64 + lane];
        #pragma unroll
        for (int ks = 0; ks < 10; ++ks) {
            bf16x8 aN, b0N, b1N, b2N;
            if (ks < 9) {
                aN  = *(const bf16x8*)(hb + row * 384 + (((ks + 1) * 32 + hi * 16) ^ ((row & 7) << 4)));
                b0N = BH[((0 * 5 + nt) * 10 + ks + 1) * 64 + lane];
                b1N = BH[((1 * 5 + nt) * 10 + ks + 1) * 64 + lane];
                b2N = BH[((2 * 5 + nt) * 10 + ks + 1) * 64 + lane];
            }
            ai = __builtin_amdgcn_mfma_f32_32x32x16_bf16(aC, b0C, ai, 0, 0, 0);
            ao = __builtin_amdgcn_mfma_f32_32x32x16_bf16(aC, b1C, ao, 0, 0, 0);
            au = __builtin_amdgcn_mfma_f32_32x32x16_bf16(aC, b2C, au, 0, 0, 0);
            aC = aN; b0C = b0N; b1C = b1N; b2C = b2N;
        }
    }

    float cvv[16];
    {
        float hp[4] = {0.f, 0.f, 0.f, 0.f};
        #pragma unroll
        for (int r = 0; r < 16; ++r) {
            int rloc = (r & 3) + 8 * (r >> 2) + 4 * hi;
            bool rv = rloc < rowsValid;
            ushort4 gv = *(const ushort4*)(gall + (long)toksL[rloc] * GROW + cc * 4);
            float fcin = (rv && colv) ? b2f(fcsum[(long)(nodeBase + rloc) * FSTR + col]) : 0.f;
            float iv = sigm(ai[r] + b2f(gv.x));
            float ov = sigm(ao[r] + b2f(gv.y));
            float uv = tanh_fast(au[r] + b2f(gv.z));
            float cv = iv * uv + fcin;
            float h = (rv && colv) ? ov * tanh_fast(cv) : 0.f;
            cvv[r] = (rv && colv) ? cv : 0.f;
            if (rv && colv) c_out[(long)(nodeBase + rloc) * MEMD + col] = cv;
            *(unsigned short*)(sm0 + rloc * 384 + ((col * 2) ^ ((rloc & 7) << 4))) = f2b(h);
            hp[r >> 2] += h;
        }
        if (writePar) {
            #pragma unroll
            for (int o = 0; o < 4; ++o) {
                float s = hp[o] + __shfl_xor(hp[o], 32);
                if (lane < 32 && colv && o * 8 < rowsValid)
                    hsumb[(long)(p0 + o) * FSTR + col] = f2b(s);
            }
        }
    }
    __syncthreads();

    if (writePar) {
        f32x16 ff = ZERO16;
        {
            bf16x8 aC = *(const bf16x8*)(sm0 + row * 384 + ((hi * 16) ^ ((row & 7) << 4)));
            bf16x8 bC = BH[((15 + nt) * 10 + 0) * 64 + lane];
            #pragma unroll
            for (int ks = 0; ks < 10; ++ks) {
                bf16x8 aN, bN;
                if (ks < 9) {
                    aN = *(const bf16x8*)(sm0 + row * 384 + (((ks + 1) * 32 + hi * 16) ^ ((row & 7) << 4)));
                    bN = BH[((15 + nt) * 10 + ks + 1) * 64 + lane];
                }
                ff = __builtin_amdgcn_mfma_f32_32x32x16_bf16(aC, bC, ff, 0, 0, 0);
                aC = aN; bC = bN;
            }
        }
        #pragma unroll
        for (int o = 0; o < 4; ++o) {
            float fx = b2f(gall[(long)ptokL[o] * GROW + cc * 4 + 3]);
            float fp = 0.f;
            #pragma unroll
            for (int q = 0; q < 4; ++q) {
                int r = o * 4 + q;
                fp += sigm(ff[r] + fx) * cvv[r];
            }
            float s = fp + __shfl_xor(fp, 32);
            if (lane < 32 && colv && o * 8 < rowsValid)
                fcsum[(long)(p0 + o) * FSTR + col] = f2b(s);
        }
    }
}

// ---- fused tail: levels 2 (64 nodes), 1 (8), 0 (1) in one block ----
__global__ __launch_bounds__(320, 2)
void tail_k(const int* __restrict__ tokens,
            const unsigned short* __restrict__ gall,
            const unsigned short* __restrict__ bph_u,
            unsigned short* __restrict__ hsumb, unsigned short* __restrict__ fcsum,
            float* __restrict__ c_out)
{
    __shared__ __align__(16) char sm0[24576];
    __shared__ int toksL[32];
    __shared__ int ptokL[4];
    const int tid = threadIdx.x, lane = tid & 63, w = tid >> 6;
    const int hi = lane >> 5, ln31 = lane & 31;
    const int nt = w;
    const bf16x8* BH = (const bf16x8*)bph_u;
    const int row = ln31;
    const int col = nt * 32 + ln31;
    const bool colv = col < MEMD;
    const int cc = colv ? col : 0;

    const int basesL[3] = {9, 1, 0};
    const int cntsL[3]  = {64, 8, 1};
    const int wpL[3]    = {1, 1, 0};

    for (int li = 0; li < 3; ++li) {
        for (int t0 = 0; t0 < cntsL[li]; t0 += 32) {
            const int nodeBase = basesL[li] + t0;
            const int rowsValid = min(32, cntsL[li] - t0);
            const int p0 = (nodeBase - 1) >> 3;
            const int writePar = wpL[li];

            if (tid < 32) toksL[tid] = tokens[nodeBase + ((tid < rowsValid) ? tid : 0)];
            if (writePar && tid < 4) ptokL[tid] = tokens[p0 + tid];
            for (int i = tid; i < 32 * 20; i += 320) {
                int r = i / 20, q = i % 20;
                int rr = (r < rowsValid) ? r : 0;
                bf16x8 v = {0,0,0,0,0,0,0,0};
                if (q < 19)
                    v = *(const bf16x8*)(hsumb + (long)(nodeBase + rr) * FSTR + q * 8);
                *(bf16x8*)(sm0 + 12288 + r * 384 + ((q * 16) ^ ((r & 7) << 4))) = v;
            }
            __syncthreads();

            f32x16 ai = ZERO16, ao = ZERO16, au = ZERO16;
            {
                const char* hb = sm0 + 12288;
                #pragma unroll
                for (int ks = 0; ks < 10; ++ks) {
                    bf16x8 a = *(const bf16x8*)(hb + row * 384 + ((ks * 32 + hi * 16) ^ ((row & 7) << 4)));
                    ai = __builtin_amdgcn_mfma_f32_32x32x16_bf16(a, BH[((0 * 5 + nt) * 10 + ks) * 64 + lane], ai, 0, 0, 0);
                    ao = __builtin_amdgcn_mfma_f32_32x32x16_bf16(a, BH[((1 * 5 + nt) * 10 + ks) * 64 + lane], ao, 0, 0, 0);
                    au = __builtin_amdgcn_mfma_f32_32x32x16_bf16(a, BH[((2 * 5 + nt) * 10 + ks) * 64 + lane], au, 0, 0, 0);
                }
            }

            float cvv[16];
            {
                float hp[4] = {0.f, 0.f, 0.f, 0.f};
                #pragma unroll
                for (int r = 0; r < 16; ++r) {
                    int rloc = (r & 3) + 8 * (r >> 2) + 4 * hi;
                    bool rv = rloc < rowsValid;
                    ushort4 gv = *(const ushort4*)(gall + (long)toksL[rloc] * GROW + cc * 4);
                    float fcin = (rv && colv) ? b2f(fcsum[(long)(nodeBase + rloc) * FSTR + col]) : 0.f;
                    float iv = sigm(ai[r] + b2f(gv.x));
                    float ov = sigm(ao[r] + b2f(gv.y));
                    float uv = tanh_fast(au[r] + b2f(gv.z));
                    float cv = iv * uv + fcin;
                    float h = (rv && colv) ? ov * tanh_fast(cv) : 0.f;
                    cvv[r] = (rv && colv) ? cv : 0.f;
                    if (rv && colv) c_out[(long)(nodeBase + rloc) * MEMD + col] = cv;
                    *(unsigned short*)(sm0 + rloc * 384 + ((col * 2) ^ ((rloc & 7) << 4))) = f2b(h);
                    hp[r >> 2] += h;
                }
                if (writePar) {
                    #pragma unroll
                    for (int o = 0; o < 4; ++o) {
                        float s = hp[o] + __shfl_xor(hp[o], 32);
                        if (lane < 32 && colv && o * 8 < rowsValid)
                            hsumb[(long)(p0 + o) * FSTR + col] = f2b(s);
                    }
                }
            }
            __syncthreads();

            if (writePar) {
                f32x16 ff = ZERO16;
                #pragma unroll
                for (int ks = 0; ks < 10; ++ks) {
                    bf16x8 a = *(const bf16x8*)(sm0 + row * 384 + ((ks * 32 + hi * 16) ^ ((row & 7) << 4)));
                    ff = __builtin_amdgcn_mfma_f32_32x32x16_bf16(a, BH[((15 + nt) * 10 + ks) * 64 + lane], ff, 0, 0, 0);
                }
                #pragma unroll
                for (int o = 0; o < 4; ++o) {
                    float fx = b2f(gall[(long)ptokL[o] * GROW + cc * 4 + 3]);
                    float fp = 0.f;
                    #pragma unroll
                    for (int q = 0; q < 4; ++q)
                        fp += sigm(ff[o * 4 + q] + fx) * cvv[o * 4 + q];
                    float s = fp + __shfl_xor(fp, 32);
                    if (lane < 32 && colv && o * 8 < rowsValid)
                        fcsum[(long)(p0 + o) * FSTR + col] = f2b(s);
                }
            }
            __syncthreads();
        }
    }
}

extern "C" void kernel_launch(void* const* d_in, const int* in_sizes, int n_in,
                              void* d_out, int out_size, void* d_ws, size_t ws_size,
                              hipStream_t stream) {
    const int*   tokens = (const int*)d_in[0];
    const float* emb = (const float*)d_in[4];
    const float* Wix = (const float*)d_in[5];  const float* bix = (const float*)d_in[6];
    const float* Wih = (const float*)d_in[7];  const float* bih = (const float*)d_in[8];
    const float* Wfx = (const float*)d_in[9];  const float* bfx = (const float*)d_in[10];
    const float* Wfh = (const float*)d_in[11]; const float* bfh = (const float*)d_in[12];
    const float* Wox = (const float*)d_in[13]; const float* box_ = (const float*)d_in[14];
    const float* Woh = (const float*)d_in[15]; const float* boh = (const float*)d_in[16];
    const float* Wux = (const float*)d_in[17]; const float* bux = (const float*)d_in[18];
    const float* Wuh = (const float*)d_in[19]; const float* buh = (const float*)d_in[20];
    float* c_out = (float*)d_out;
    char* ws = (char*)d_ws;

    unsigned short* gall  = (unsigned short*)(ws + GALL_OFF);
    unsigned char*  fhx   = (unsigned char*)(ws + FHX_OFF);
    unsigned short* hsumb = (unsigned short*)(ws + HSB_OFF);
    unsigned short* htmp  = (unsigned short*)(ws + HSB_OFF);   // alias, stream-ordered
    unsigned short* fcs   = (unsigned short*)(ws + FCS_OFF);
    unsigned short* bpx   = (unsigned short*)(ws + BPX_OFF);
    unsigned short* bph   = (unsigned short*)(ws + BPH_OFF);

    pack_w<<<128, 512, 0, stream>>>(Wix, Wox, Wux, Wfx, Wih, Woh, Wuh, Wfh, bpx, bph);
    vocab_gemm<<<(VOCAB + 63) / 64, 640, 0, stream>>>(
        emb, bix, bih, box_, boh, bux, buh, bfx, bfh, bpx, gall);
    hleaf_k<<<(VOCAB * FSTR + 255) / 256, 256, 0, stream>>>(gall, htmp);
    fhx_gemm<<<(VOCAB + 31) / 32, 320, 0, stream>>>(htmp, bph, fhx);
    leaf_csum<<<16384, 320, 0, stream>>>(tokens, gall, fhx, hsumb, fcs, c_out);

    static const int bases[7] = {0, 1, 9, 73, 585, 4681, 37449};
    static const int cnts[7]  = {1, 8, 64, 512, 4096, 32768, 262144};
    for (int d = 5; d >= 3; --d) {
        int grid = (cnts[d] + 31) / 32;
        level_k<<<grid, 320, 0, stream>>>(
            tokens, gall, bph, hsumb, fcs, c_out, bases[d], cnts[d], 1);
    }
    tail_k<<<1, 320, 0, stream>>>(tokens, gall, bph, hsumb, fcs, c_out);
}

// Round 10
// 278.754 us; speedup vs baseline: 1.1937x; 1.1937x over previous
//
#include <hip/hip_runtime.h>

// ChildSumTreeLSTM, complete 8-ary tree, 7 levels, N=299593, MEM=150, IN=300.
// Level d occupies [(8^d-1)/7, (8^(d+1)-1)/7); children of p: 8p+1..8p+8.
// v10: per-vocab tables cleaf/hleaf/fhx; per-internal-node pre-activation
// table xint[n][col][4] (i,o,u,f; biases folded). leaf_csum = pure gather +
// 1 sigmoid. GEMMs restructured: 32-row/5-wave blocks, 1 A-read -> 3-4 MFMAs,
// 2-deep B prefetch. cleaf lives in d_out's internal region (stream-ordered
// scratch: consumed by leaf_csum before level_k(5)/level_k(4)/tail overwrite).

#define MEMD  150
#define IND   300
#define NINT  37449
#define VOCAB 50000
#define XROW  608          // ushorts per xint row (152 cols x 4 gates)
#define FSTR  152          // cleaf/hleaf/fhx/hsum/fcs row stride (elements)

typedef short bf16x8 __attribute__((ext_vector_type(8)));
typedef float f32x16 __attribute__((ext_vector_type(16)));
#define ZERO16 {0,0,0,0,0,0,0,0,0,0,0,0,0,0,0,0}

// ws layout (bytes); high-water 91,714,800 <= 95,869,760 proven safe (R1)
#define XINT_OFF 0ul           // ushort [NINT][608]      45,537,984
#define HLF_OFF  45540000ul    // bf16 [VOCAB][152]       15,200,000
#define FHX_OFF  60740000ul    // u8 fp8 [VOCAB][152]      7,600,000
#define HSB_OFF  68340000ul    // bf16 [NINT][152]        11,384,496
#define FCS_OFF  79730000ul    // bf16 [NINT][152]        11,384,496
#define BPX_OFF  91120000ul    // bf16 B-frags x [4][5][19][64][8]  389,120
#define BPH_OFF  91510000ul    // bf16 B-frags h [4][5][10][64][8]  204,800

__device__ __forceinline__ float b2f(unsigned short u) {
    union { unsigned int i; float f; } v; v.i = ((unsigned int)u) << 16; return v.f;
}
__device__ __forceinline__ unsigned short f2b(float f) {
    union { float f; unsigned int i; } v; v.f = f;
    unsigned int x = v.i;
    x += 0x7fffu + ((x >> 16) & 1u);
    return (unsigned short)(x >> 16);
}
__device__ __forceinline__ float sigm(float x) {
    return __builtin_amdgcn_rcpf(1.0f + __expf(-x));
}
__device__ __forceinline__ float tanh_fast(float x) {
    float e = __expf(2.0f * x);
    return 1.0f - 2.0f * __builtin_amdgcn_rcpf(e + 1.0f);
}
__device__ __forceinline__ unsigned char f2e4m3(float f) {
    union { float f; unsigned u; } v; v.f = f;
    unsigned s = (v.u >> 31) << 7;
    float af = fabsf(f);
    if (af >= 448.f) return (unsigned char)(s | 0x7E);
    if (af < 0.015625f) {
        int m = (int)(af * 512.f + 0.5f);
        if (m > 7) m = 7;
        return (unsigned char)(s | m);
    }
    unsigned u = v.u & 0x7fffffffu;
    u += 0x7ffffu + ((u >> 20) & 1u);
    int ef = (int)(u >> 23) - 120;
    unsigned m = (u >> 20) & 7u;
    if (ef < 1) { ef = 1; m = 0; }
    if (ef > 15) { ef = 15; m = 6; }
    return (unsigned char)(s | (ef << 3) | m);
}
__device__ __forceinline__ float e4m3f(unsigned char u) {
    unsigned s = (u >> 7) & 1u, ef = (u >> 3) & 15u, m = u & 7u;
    if (ef == 0) {
        float r = (float)m * 0.001953125f;
        return s ? -r : r;
    }
    union { unsigned u; float f; } v;
    v.u = (s << 31) | ((ef + 120) << 23) | (m << 20);
    return v.f;
}

// ---- pack weights into 32x32x16 B-fragment order (verified R3-R9) ----
__global__ void pack_w(const float* __restrict__ Wix, const float* __restrict__ Wox,
                       const float* __restrict__ Wux, const float* __restrict__ Wfx,
                       const float* __restrict__ Wih, const float* __restrict__ Woh,
                       const float* __restrict__ Wuh, const float* __restrict__ Wfh,
                       unsigned short* __restrict__ bpx, unsigned short* __restrict__ bph)
{
    const int total_x = 4 * 5 * 19 * 512;
    const int total_h = 4 * 5 * 10 * 512;
    for (int i = blockIdx.x * blockDim.x + threadIdx.x; i < total_x + total_h;
         i += gridDim.x * blockDim.x) {
        if (i < total_x) {
            int e = i & 7, lane = (i >> 3) & 63, rest = i >> 9;
            int ks = rest % 19; rest /= 19;
            int nt = rest % 5;  int g = rest / 5;
            int col = nt * 32 + (lane & 31);
            int k = ks * 16 + ((lane >> 5) << 3) + e;
            const float* W = (g == 0) ? Wix : (g == 1) ? Wox : (g == 2) ? Wux : Wfx;
            bpx[i] = f2b((col < MEMD && k < IND) ? W[col * IND + k] : 0.f);
        } else {
            int j = i - total_x;
            int e = j & 7, lane = (j >> 3) & 63, rest = j >> 9;
            int ks = rest % 10; rest /= 10;
            int nt = rest % 5;  int g = rest / 5;
            int col = nt * 32 + (lane & 31);
            int k = ks * 16 + ((lane >> 5) << 3) + e;
            const float* W = (g == 0) ? Wih : (g == 1) ? Woh : (g == 2) ? Wuh : Wfh;
            bph[j] = f2b((col < MEMD && k < MEMD) ? W[col * MEMD + k] : 0.f);
        }
    }
}

// ---- per-vocab leaf tables: cleaf (into d_out scratch) + hleaf ----
__global__ __launch_bounds__(320, 2)
void cleaf_gemm(const float* __restrict__ emb,
                const float* __restrict__ bix, const float* __restrict__ bih,
                const float* __restrict__ box_, const float* __restrict__ boh,
                const float* __restrict__ bux, const float* __restrict__ buh,
                const unsigned short* __restrict__ bpx_u,
                unsigned short* __restrict__ cleafU, unsigned short* __restrict__ hleaf)
{
    __shared__ __align__(16) char sm0[20480];
    const int tid = threadIdx.x, lane = tid & 63, w = tid >> 6;
    const int hi = lane >> 5, ln31 = lane & 31;
    const int tile0 = blockIdx.x * 32;
    const int rowsValid = min(32, VOCAB - tile0);

    for (int i = tid; i < 32 * 40; i += 320) {
        int r = i / 40, q = i % 40;
        int rr = (r < rowsValid) ? r : 0;
        const float* er = emb + (long)(tile0 + rr) * IND;
        float4 v0 = {0.f,0.f,0.f,0.f}, v1 = {0.f,0.f,0.f,0.f};
        if (q < 38) v0 = *(const float4*)(er + q * 8);
        if (q < 37) v1 = *(const float4*)(er + q * 8 + 4);
        bf16x8 p;
        p[0]=(short)f2b(v0.x); p[1]=(short)f2b(v0.y); p[2]=(short)f2b(v0.z); p[3]=(short)f2b(v0.w);
        p[4]=(short)f2b(v1.x); p[5]=(short)f2b(v1.y); p[6]=(short)f2b(v1.z); p[7]=(short)f2b(v1.w);
        *(bf16x8*)(sm0 + r * 640 + ((q * 16) ^ ((r & 7) << 4))) = p;
    }
    __syncthreads();

    const bf16x8* BX = (const bf16x8*)bpx_u;
    const int row = ln31, nt = w;
    const int col = nt * 32 + ln31;
    const bool colv = col < MEMD;
    const int cc = colv ? col : 0;

    f32x16 a0 = ZERO16, a1 = ZERO16, a2 = ZERO16;
    {
        bf16x8 aC = *(const bf16x8*)(sm0 + row * 640 + ((hi * 16) ^ ((row & 7) << 4)));
        bf16x8 b0C = BX[((0 * 5 + nt) * 19 + 0) * 64 + lane];
        bf16x8 b1C = BX[((1 * 5 + nt) * 19 + 0) * 64 + lane];
        bf16x8 b2C = BX[((2 * 5 + nt) * 19 + 0) * 64 + lane];
        #pragma unroll
        for (int ks = 0; ks < 19; ++ks) {
            bf16x8 aN, b0N, b1N, b2N;
            if (ks < 18) {
                aN  = *(const bf16x8*)(sm0 + row * 640 + (((ks + 1) * 32 + hi * 16) ^ ((row & 7) << 4)));
                b0N = BX[((0 * 5 + nt) * 19 + ks + 1) * 64 + lane];
                b1N = BX[((1 * 5 + nt) * 19 + ks + 1) * 64 + lane];
                b2N = BX[((2 * 5 + nt) * 19 + ks + 1) * 64 + lane];
            }
            a0 = __builtin_amdgcn_mfma_f32_32x32x16_bf16(aC, b0C, a0, 0, 0, 0);
            a1 = __builtin_amdgcn_mfma_f32_32x32x16_bf16(aC, b1C, a1, 0, 0, 0);
            a2 = __builtin_amdgcn_mfma_f32_32x32x16_bf16(aC, b2C, a2, 0, 0, 0);
            aC = aN; b0C = b0N; b1C = b1N; b2C = b2N;
        }
    }
    const float bi = bix[cc] + bih[cc];
    const float bo = box_[cc] + boh[cc];
    const float bu = bux[cc] + buh[cc];
    #pragma unroll
    for (int r = 0; r < 16; ++r) {
        int rloc = (r & 3) + 8 * (r >> 2) + 4 * hi;
        float iv = sigm(a0[r] + bi);
        float ov = sigm(a1[r] + bo);
        float uv = tanh_fast(a2[r] + bu);
        float cv = iv * uv;
        float h = ov * tanh_fast(cv);
        if (rloc < rowsValid && colv) {
            long o = (long)(tile0 + rloc) * FSTR + col;
            cleafU[o] = f2b(cv);
            hleaf[o] = f2b(h);
        }
    }
}

// ---- per-internal-node pre-activations xint[n][col][4] ----
__global__ __launch_bounds__(320, 2)
void xint_gemm(const int* __restrict__ tokens, const float* __restrict__ emb,
               const float* __restrict__ bix, const float* __restrict__ bih,
               const float* __restrict__ box_, const float* __restrict__ boh,
               const float* __restrict__ bux, const float* __restrict__ buh,
               const float* __restrict__ bfx, const float* __restrict__ bfh,
               const unsigned short* __restrict__ bpx_u,
               unsigned short* __restrict__ xint)
{
    __shared__ __align__(16) char sm0[20480];
    __shared__ int toksL[32];
    const int tid = threadIdx.x, lane = tid & 63, w = tid >> 6;
    const int hi = lane >> 5, ln31 = lane & 31;
    const int tile0 = blockIdx.x * 32;
    const int rowsValid = min(32, NINT - tile0);

    if (tid < 32) toksL[tid] = tokens[tile0 + ((tid < rowsValid) ? tid : 0)];
    __syncthreads();
    for (int i = tid; i < 32 * 40; i += 320) {
        int r = i / 40, q = i % 40;
        const float* er = emb + (long)toksL[r] * IND;
        float4 v0 = {0.f,0.f,0.f,0.f}, v1 = {0.f,0.f,0.f,0.f};
        if (q < 38) v0 = *(const float4*)(er + q * 8);
        if (q < 37) v1 = *(const float4*)(er + q * 8 + 4);
        bf16x8 p;
        p[0]=(short)f2b(v0.x); p[1]=(short)f2b(v0.y); p[2]=(short)f2b(v0.z); p[3]=(short)f2b(v0.w);
        p[4]=(short)f2b(v1.x); p[5]=(short)f2b(v1.y); p[6]=(short)f2b(v1.z); p[7]=(short)f2b(v1.w);
        *(bf16x8*)(sm0 + r * 640 + ((q * 16) ^ ((r & 7) << 4))) = p;
    }
    __syncthreads();

    const bf16x8* BX = (const bf16x8*)bpx_u;
    const int row = ln31, nt = w;
    const int col = nt * 32 + ln31;
    const bool colv = col < MEMD;
    const int cc = colv ? col : 0;

    f32x16 a0 = ZERO16, a1 = ZERO16, a2 = ZERO16, a3 = ZERO16;
    {
        bf16x8 aC = *(const bf16x8*)(sm0 + row * 640 + ((hi * 16) ^ ((row & 7) << 4)));
        bf16x8 b0C = BX[((0 * 5 + nt) * 19 + 0) * 64 + lane];
        bf16x8 b1C = BX[((1 * 5 + nt) * 19 + 0) * 64 + lane];
        bf16x8 b2C = BX[((2 * 5 + nt) * 19 + 0) * 64 + lane];
        bf16x8 b3C = BX[((3 * 5 + nt) * 19 + 0) * 64 + lane];
        #pragma unroll
        for (int ks = 0; ks < 19; ++ks) {
            bf16x8 aN, b0N, b1N, b2N, b3N;
            if (ks < 18) {
                aN  = *(const bf16x8*)(sm0 + row * 640 + (((ks + 1) * 32 + hi * 16) ^ ((row & 7) << 4)));
                b0N = BX[((0 * 5 + nt) * 19 + ks + 1) * 64 + lane];
                b1N = BX[((1 * 5 + nt) * 19 + ks + 1) * 64 + lane];
                b2N = BX[((2 * 5 + nt) * 19 + ks + 1) * 64 + lane];
                b3N = BX[((3 * 5 + nt) * 19 + ks + 1) * 64 + lane];
            }
            a0 = __builtin_amdgcn_mfma_f32_32x32x16_bf16(aC, b0C, a0, 0, 0, 0);
            a1 = __builtin_amdgcn_mfma_f32_32x32x16_bf16(aC, b1C, a1, 0, 0, 0);
            a2 = __builtin_amdgcn_mfma_f32_32x32x16_bf16(aC, b2C, a2, 0, 0, 0);
            a3 = __builtin_amdgcn_mfma_f32_32x32x16_bf16(aC, b3C, a3, 0, 0, 0);
            aC = aN; b0C = b0N; b1C = b1N; b2C = b2N; b3C = b3N;
        }
    }
    const float bi = bix[cc] + bih[cc];
    const float bo = box_[cc] + boh[cc];
    const float bu = bux[cc] + buh[cc];
    const float bf = bfx[cc] + bfh[cc];
    #pragma unroll
    for (int r = 0; r < 16; ++r) {
        int rloc = (r & 3) + 8 * (r >> 2) + 4 * hi;
        if (rloc < rowsValid && colv) {
            ushort4 gv;
            gv.x = f2b(a0[r] + bi);
            gv.y = f2b(a1[r] + bo);
            gv.z = f2b(a2[r] + bu);
            gv.w = f2b(a3[r] + bf);
            *(ushort4*)(xint + (long)(tile0 + rloc) * XROW + col * 4) = gv;
        }
    }
}

// ---- fhx(v) = Wfh · h_leaf(v), fp8 e4m3 ----
__global__ __launch_bounds__(320, 4)
void fhx_gemm(const unsigned short* __restrict__ hleaf,
              const unsigned short* __restrict__ bph_u,
              unsigned char* __restrict__ fhx)
{
    __shared__ __align__(16) char sm0[12288];
    const int tid = threadIdx.x, lane = tid & 63, w = tid >> 6;
    const int hi = lane >> 5, ln31 = lane & 31;
    const int tile0 = blockIdx.x * 32;
    const int rowsValid = min(32, VOCAB - tile0);
    const int nt = w;

    for (int i = tid; i < 32 * 20; i += 320) {
        int r = i / 20, q = i % 20;
        int rr = (r < rowsValid) ? r : 0;
        bf16x8 v = {0,0,0,0,0,0,0,0};
        if (q < 19) v = *(const bf16x8*)(hleaf + (long)(tile0 + rr) * FSTR + q * 8);
        *(bf16x8*)(sm0 + r * 384 + ((q * 16) ^ ((r & 7) << 4))) = v;
    }
    __syncthreads();

    const bf16x8* BH = (const bf16x8*)bph_u;
    const int row = ln31;
    f32x16 ff = ZERO16;
    #pragma unroll
    for (int ks = 0; ks < 10; ++ks) {
        bf16x8 a = *(const bf16x8*)(sm0 + row * 384 + ((ks * 32 + hi * 16) ^ ((row & 7) << 4)));
        ff = __builtin_amdgcn_mfma_f32_32x32x16_bf16(a, BH[((15 + nt) * 10 + ks) * 64 + lane], ff, 0, 0, 0);
    }
    const int col = nt * 32 + ln31;
    if (col < MEMD) {
        #pragma unroll
        for (int r = 0; r < 16; ++r) {
            int rloc = (r & 3) + 8 * (r >> 2) + 4 * hi;
            if (rloc < rowsValid)
                fhx[(long)(tile0 + rloc) * FSTR + col] = f2e4m3(ff[r]);
        }
    }
}

// ---- leaf level: table gathers only ----
__global__ __launch_bounds__(320, 8)
void leaf_csum(const int* __restrict__ tokens,
               const unsigned short* __restrict__ cleafU,
               const unsigned short* __restrict__ hleaf,
               const unsigned char* __restrict__ fhx,
               const unsigned short* __restrict__ xint,
               unsigned short* __restrict__ hsumb, unsigned short* __restrict__ fcs,
               float* __restrict__ c_out)
{
    __shared__ int ctok[16];
    const int tid = threadIdx.x;
    const int pl = tid / 160;
    const int col0 = tid % 160;
    const bool colv = col0 < MEMD;
    const int col = colv ? col0 : (MEMD - 1);
    const int pnode = 4681 + blockIdx.x * 2 + pl;
    const long cbase = 8L * pnode + 1;
    if (tid < 16) ctok[tid] = tokens[37449 + blockIdx.x * 16 + tid];
    __syncthreads();

    const float fxp = b2f(xint[(long)pnode * XROW + col * 4 + 3]);
    float hs = 0.f, fc = 0.f;
    #pragma unroll
    for (int k = 0; k < 8; ++k) {
        int ct = ctok[pl * 8 + k];
        long o = (long)ct * FSTR + col;
        float cv = b2f(cleafU[o]);
        float h  = b2f(hleaf[o]);
        float f  = sigm(e4m3f(fhx[o]) + fxp);
        hs += h;
        fc += f * cv;
        if (colv) c_out[(cbase + k) * MEMD + col] = cv;
    }
    if (colv) {
        hsumb[(long)pnode * FSTR + col] = f2b(hs);
        fcs[(long)pnode * FSTR + col]  = f2b(fc);
    }
}

// ---- internal-level kernel (levels 5..3) ----
__global__ __launch_bounds__(320, 2)
void level_k(const unsigned short* __restrict__ xint,
             const unsigned short* __restrict__ bph_u,
             unsigned short* __restrict__ hsumb, unsigned short* __restrict__ fcsum,
             float* __restrict__ c_out, int base, int cnt, int writePar)
{
    __shared__ __align__(16) char sm0[24576];
    const int tid = threadIdx.x, lane = tid & 63, w = tid >> 6;
    const int hi = lane >> 5, ln31 = lane & 31;
    const int tile0 = blockIdx.x * 32;
    const int nodeBase = base + tile0;
    const int rowsValid = min(32, cnt - tile0);
    const int p0 = (nodeBase - 1) >> 3;
    const int nt = w;

    for (int i = tid; i < 32 * 20; i += 320) {
        int r = i / 20, q = i % 20;
        int rr = (r < rowsValid) ? r : 0;
        bf16x8 v = {0,0,0,0,0,0,0,0};
        if (q < 19)
            v = *(const bf16x8*)(hsumb + (long)(nodeBase + rr) * FSTR + q * 8);
        *(bf16x8*)(sm0 + 12288 + r * 384 + ((q * 16) ^ ((r & 7) << 4))) = v;
    }
    __syncthreads();

    const bf16x8* BH = (const bf16x8*)bph_u;
    const int row = ln31;
    const int col = nt * 32 + ln31;
    const bool colv = col < MEMD;
    const int cc = colv ? col : 0;

    f32x16 ai = ZERO16, ao = ZERO16, au = ZERO16;
    {
        const char* hb = sm0 + 12288;
        bf16x8 aC = *(const bf16x8*)(hb + row * 384 + ((hi * 16) ^ ((row & 7) << 4)));
        bf16x8 b0C = BH[((0 * 5 + nt) * 10 + 0) * 64 + lane];
        bf16x8 b1C = BH[((1 * 5 + nt) * 10 + 0) * 64 + lane];
        bf16x8 b2C = BH[((2 * 5 + nt) * 10 + 0) * 64 + lane];
        #pragma unroll
        for (int ks = 0; ks < 10; ++ks) {
            bf16x8 aN, b0N, b1N, b2N;
            if (ks < 9) {
                aN  = *(const bf16x8*)(hb + row * 384 + (((ks + 1) * 32 + hi * 16) ^ ((row & 7) << 4)));
                b0N = BH[((0 * 5 + nt) * 10 + ks + 1) * 64 + lane];
                b1N = BH[((1 * 5 + nt) * 10 + ks + 1) * 64 + lane];
                b2N = BH[((2 * 5 + nt) * 10 + ks + 1) * 64 + lane];
            }
            ai = __builtin_amdgcn_mfma_f32_32x32x16_bf16(aC, b0C, ai, 0, 0, 0);
            ao = __builtin_amdgcn_mfma_f32_32x32x16_bf16(aC, b1C, ao, 0, 0, 0);
            au = __builtin_amdgcn_mfma_f32_32x32x16_bf16(aC, b2C, au, 0, 0, 0);
            aC = aN; b0C = b0N; b1C = b1N; b2C = b2N;
        }
    }

    float cvv[16];
    {
        float hp[4] = {0.f, 0.f, 0.f, 0.f};
        #pragma unroll
        for (int r = 0; r < 16; ++r) {
            int rloc = (r & 3) + 8 * (r >> 2) + 4 * hi;
            bool rv = rloc < rowsValid;
            int rr = rv ? rloc : 0;
            ushort4 gv = *(const ushort4*)(xint + (long)(nodeBase + rr) * XROW + cc * 4);
            float fcin = (rv && colv) ? b2f(fcsum[(long)(nodeBase + rloc) * FSTR + col]) : 0.f;
            float iv = sigm(ai[r] + b2f(gv.x));
            float ov = sigm(ao[r] + b2f(gv.y));
            float uv = tanh_fast(au[r] + b2f(gv.z));
            float cv = iv * uv + fcin;
            float h = (rv && colv) ? ov * tanh_fast(cv) : 0.f;
            cvv[r] = (rv && colv) ? cv : 0.f;
            if (rv && colv) c_out[(long)(nodeBase + rloc) * MEMD + col] = cv;
            *(unsigned short*)(sm0 + rloc * 384 + ((col * 2) ^ ((rloc & 7) << 4))) = f2b(h);
            hp[r >> 2] += h;
        }
        if (writePar) {
            #pragma unroll
            for (int o = 0; o < 4; ++o) {
                float s = hp[o] + __shfl_xor(hp[o], 32);
                if (lane < 32 && colv && o * 8 < rowsValid)
                    hsumb[(long)(p0 + o) * FSTR + col] = f2b(s);
            }
        }
    }
    __syncthreads();

    if (writePar) {
        f32x16 ff = ZERO16;
        {
            bf16x8 aC = *(const bf16x8*)(sm0 + row * 384 + ((hi * 16) ^ ((row & 7) << 4)));
            bf16x8 bC = BH[((15 + nt) * 10 + 0) * 64 + lane];
            #pragma unroll
            for (int ks = 0; ks < 10; ++ks) {
                bf16x8 aN, bN;
                if (ks < 9) {
                    aN = *(const bf16x8*)(sm0 + row * 384 + (((ks + 1) * 32 + hi * 16) ^ ((row & 7) << 4)));
                    bN = BH[((15 + nt) * 10 + ks + 1) * 64 + lane];
                }
                ff = __builtin_amdgcn_mfma_f32_32x32x16_bf16(aC, bC, ff, 0, 0, 0);
                aC = aN; bC = bN;
            }
        }
        #pragma unroll
        for (int o = 0; o < 4; ++o) {
            float fx = b2f(xint[(long)(p0 + o) * XROW + cc * 4 + 3]);
            float fp = 0.f;
            #pragma unroll
            for (int q = 0; q < 4; ++q) {
                int r = o * 4 + q;
                fp += sigm(ff[r] + fx) * cvv[r];
            }
            float s = fp + __shfl_xor(fp, 32);
            if (lane < 32 && colv && o * 8 < rowsValid)
                fcsum[(long)(p0 + o) * FSTR + col] = f2b(s);
        }
    }
}

// ---- fused tail: levels 2 (64 nodes), 1 (8), 0 (1) ----
__global__ __launch_bounds__(320, 2)
void tail_k(const unsigned short* __restrict__ xint,
            const unsigned short* __restrict__ bph_u,
            unsigned short* __restrict__ hsumb, unsigned short* __restrict__ fcsum,
            float* __restrict__ c_out)
{
    __shared__ __align__(16) char sm0[24576];
    const int tid = threadIdx.x, lane = tid & 63, w = tid >> 6;
    const int hi = lane >> 5, ln31 = lane & 31;
    const int nt = w;
    const bf16x8* BH = (const bf16x8*)bph_u;
    const int row = ln31;
    const int col = nt * 32 + ln31;
    const bool colv = col < MEMD;
    const int cc = colv ? col : 0;

    const int basesL[3] = {9, 1, 0};
    const int cntsL[3]  = {64, 8, 1};
    const int wpL[3]    = {1, 1, 0};

    for (int li = 0; li < 3; ++li) {
        const int nodeBase = basesL[li];
        const int rowsValid = min(32, cntsL[li]);
        const int p0 = (nodeBase - 1) >> 3;
        const int writePar = wpL[li];
        for (int t0 = 0; t0 < cntsL[li]; t0 += 32) {
            const int nb = nodeBase + t0;
            const int rv32 = min(32, cntsL[li] - t0);
            const int pp0 = (nb - 1) >> 3;

            for (int i = tid; i < 32 * 20; i += 320) {
                int r = i / 20, q = i % 20;
                int rr = (r < rv32) ? r : 0;
                bf16x8 v = {0,0,0,0,0,0,0,0};
                if (q < 19)
                    v = *(const bf16x8*)(hsumb + (long)(nb + rr) * FSTR + q * 8);
                *(bf16x8*)(sm0 + 12288 + r * 384 + ((q * 16) ^ ((r & 7) << 4))) = v;
            }
            __syncthreads();

            f32x16 ai = ZERO16, ao = ZERO16, au = ZERO16;
            {
                const char* hb = sm0 + 12288;
                #pragma unroll
                for (int ks = 0; ks < 10; ++ks) {
                    bf16x8 a = *(const bf16x8*)(hb + row * 384 + ((ks * 32 + hi * 16) ^ ((row & 7) << 4)));
                    ai = __builtin_amdgcn_mfma_f32_32x32x16_bf16(a, BH[((0 * 5 + nt) * 10 + ks) * 64 + lane], ai, 0, 0, 0);
                    ao = __builtin_amdgcn_mfma_f32_32x32x16_bf16(a, BH[((1 * 5 + nt) * 10 + ks) * 64 + lane], ao, 0, 0, 0);
                    au = __builtin_amdgcn_mfma_f32_32x32x16_bf16(a, BH[((2 * 5 + nt) * 10 + ks) * 64 + lane], au, 0, 0, 0);
                }
            }

            float cvv[16];
            {
                float hp[4] = {0.f, 0.f, 0.f, 0.f};
                #pragma unroll
                for (int r = 0; r < 16; ++r) {
                    int rloc = (r & 3) + 8 * (r >> 2) + 4 * hi;
                    bool rv = rloc < rv32;
                    int rr = rv ? rloc : 0;
                    ushort4 gv = *(const ushort4*)(xint + (long)(nb + rr) * XROW + cc * 4);
                    float fcin = (rv && colv) ? b2f(fcsum[(long)(nb + rloc) * FSTR + col]) : 0.f;
                    float iv = sigm(ai[r] + b2f(gv.x));
                    float ov = sigm(ao[r] + b2f(gv.y));
                    float uv = tanh_fast(au[r] + b2f(gv.z));
                    float cv = iv * uv + fcin;
                    float h = (rv && colv) ? ov * tanh_fast(cv) : 0.f;
                    cvv[r] = (rv && colv) ? cv : 0.f;
                    if (rv && colv) c_out[(long)(nb + rloc) * MEMD + col] = cv;
                    *(unsigned short*)(sm0 + rloc * 384 + ((col * 2) ^ ((rloc & 7) << 4))) = f2b(h);
                    hp[r >> 2] += h;
                }
                if (writePar) {
                    #pragma unroll
                    for (int o = 0; o < 4; ++o) {
                        float s = hp[o] + __shfl_xor(hp[o], 32);
                        if (lane < 32 && colv && o * 8 < rv32)
                            hsumb[(long)(pp0 + o) * FSTR + col] = f2b(s);
                    }
                }
            }
            __syncthreads();

            if (writePar) {
                f32x16 ff = ZERO16;
                #pragma unroll
                for (int ks = 0; ks < 10; ++ks) {
                    bf16x8 a = *(const bf16x8*)(sm0 + row * 384 + ((ks * 32 + hi * 16) ^ ((row & 7) << 4)));
                    ff = __builtin_amdgcn_mfma_f32_32x32x16_bf16(a, BH[((15 + nt) * 10 + ks) * 64 + lane], ff, 0, 0, 0);
                }
                #pragma unroll
                for (int o = 0; o < 4; ++o) {
                    float fx = b2f(xint[(long)(pp0 + o) * XROW + cc * 4 + 3]);
                    float fp = 0.f;
                    #pragma unroll
                    for (int q = 0; q < 4; ++q)
                        fp += sigm(ff[o * 4 + q] + fx) * cvv[o * 4 + q];
                    float s = fp + __shfl_xor(fp, 32);
                    if (lane < 32 && colv && o * 8 < rv32)
                        fcsum[(long)(pp0 + o) * FSTR + col] = f2b(s);
                }
            }
            __syncthreads();
        }
    }
}

extern "C" void kernel_launch(void* const* d_in, const int* in_sizes, int n_in,
                              void* d_out, int out_size, void* d_ws, size_t ws_size,
                              hipStream_t stream) {
    const int*   tokens = (const int*)d_in[0];
    const float* emb = (const float*)d_in[4];
    const float* Wix = (const float*)d_in[5];  const float* bix = (const float*)d_in[6];
    const float* Wih = (const float*)d_in[7];  const float* bih = (const float*)d_in[8];
    const float* Wfx = (const float*)d_in[9];  const float* bfx = (const float*)d_in[10];
    const float* Wfh = (const float*)d_in[11]; const float* bfh = (const float*)d_in[12];
    const float* Wox = (const float*)d_in[13]; const float* box_ = (const float*)d_in[14];
    const float* Woh = (const float*)d_in[15]; const float* boh = (const float*)d_in[16];
    const float* Wux = (const float*)d_in[17]; const float* bux = (const float*)d_in[18];
    const float* Wuh = (const float*)d_in[19]; const float* buh = (const float*)d_in[20];
    float* c_out = (float*)d_out;
    char* ws = (char*)d_ws;

    unsigned short* xint  = (unsigned short*)(ws + XINT_OFF);
    unsigned short* hleaf = (unsigned short*)(ws + HLF_OFF);
    unsigned char*  fhx   = (unsigned char*)(ws + FHX_OFF);
    unsigned short* hsumb = (unsigned short*)(ws + HSB_OFF);
    unsigned short* fcs   = (unsigned short*)(ws + FCS_OFF);
    unsigned short* bpx   = (unsigned short*)(ws + BPX_OFF);
    unsigned short* bph   = (unsigned short*)(ws + BPH_OFF);
    unsigned short* cleafU = (unsigned short*)d_out;   // scratch in internal-c region,
                                                       // dead before level_k/tail overwrite

    pack_w<<<128, 512, 0, stream>>>(Wix, Wox, Wux, Wfx, Wih, Woh, Wuh, Wfh, bpx, bph);
    cleaf_gemm<<<(VOCAB + 31) / 32, 320, 0, stream>>>(
        emb, bix, bih, box_, boh, bux, buh, bpx, cleafU, hleaf);
    xint_gemm<<<(NINT + 31) / 32, 320, 0, stream>>>(
        tokens, emb, bix, bih, box_, boh, bux, buh, bfx, bfh, bpx, xint);
    fhx_gemm<<<(VOCAB + 31) / 32, 320, 0, stream>>>(hleaf, bph, fhx);
    leaf_csum<<<16384, 320, 0, stream>>>(tokens, cleafU, hleaf, fhx, xint, hsumb, fcs, c_out);

    static const int bases[3] = {4681, 585, 73};
    static const int cnts[3]  = {32768, 4096, 512};
    for (int d = 0; d < 3; ++d) {
        int grid = (cnts[d] + 31) / 32;
        level_k<<<grid, 320, 0, stream>>>(
            xint, bph, hsumb, fcs, c_out, bases[d], cnts[d], 1);
    }
    tail_k<<<1, 320, 0, stream>>>(xint, bph, hsumb, fcs, c_out);
}